// Round 1
// baseline (967.265 us; speedup 1.0000x reference)
//
#include <hip/hip_runtime.h>
#include <stdint.h>

// AttractorDynamics: sigma = iterate(tanh(drive + (sigma @ J^T)/tau), 10)
// B=16384, M=1024, A=512, tau=0.1, sigma0=0.
// R3: settling loop fused into ONE persistent-tile kernel (settle_kernel).
//  - Rows are independent through the recurrence -> each block owns 64 rows,
//    sigma lives in LDS (64x512 bf16, granule-XOR swizzle), drive lives in
//    registers (C/D layout), NOTHING round-trips HBM between steps.
//  - J (hi/lo bf16, L2-resident 1MB) is read straight into B-fragments from
//    global (full-line consumption: hi/lo + both 64B halves issued adjacent),
//    eliminating J LDS staging + all k-loop barriers.
//  - 256 blocks x 512 threads = 1 block/CU, 8 waves, wave tile 64x64.
// drive_kernel unchanged from R2 except the sigma1 store is dropped
// (sigma1 = tanh(drive) is now computed inside settle_kernel).

#define B_DIM 16384
#define M_DIM 1024
#define A_DIM 512

typedef short bf16x8 __attribute__((ext_vector_type(8)));
typedef float f32x4 __attribute__((ext_vector_type(4)));

__device__ __forceinline__ unsigned short f2bf(float f) {
  unsigned int u = __float_as_uint(f);
  unsigned int r = (u + 0x7FFFu + ((u >> 16) & 1u)) >> 16;  // RNE
  return (unsigned short)r;
}
__device__ __forceinline__ float bf2f(unsigned short s) {
  return __uint_as_float(((unsigned int)s) << 16);
}
__device__ __forceinline__ float fast_tanh(float x) {
  float t = __expf(2.0f * x);
  return fmaf(-2.0f, __builtin_amdgcn_rcpf(t + 1.0f), 1.0f);
}

// ---- prep: split fp32 -> bf16 hi + bf16 lo (optionally pre-scaled) ----
__global__ void split_kernel(const float* __restrict__ src,
                             unsigned short* __restrict__ hi,
                             unsigned short* __restrict__ lo,
                             int n, float scale) {
  int i = blockIdx.x * 256 + threadIdx.x;
  if (i < n) {
    float v = src[i] * scale;
    unsigned short h = f2bf(v);
    hi[i] = h;
    lo[i] = f2bf(v - bf2f(h));
  }
}

// ---- drive GEMM: drive = x@W^T + b (fp32 out; sigma1 handled in settle) ----
__global__ __launch_bounds__(256) void drive_kernel(
    const float* __restrict__ x, const unsigned short* __restrict__ Whi,
    const unsigned short* __restrict__ Wlo, const float* __restrict__ bias,
    float* __restrict__ drive) {
  __shared__ __align__(16) unsigned short Ah[128][40];
  __shared__ __align__(16) unsigned short Al[128][40];
  __shared__ __align__(16) unsigned short Bh[128][40];
  __shared__ __align__(16) unsigned short Bl[128][40];

  const int t = threadIdx.x;
  const int bm = blockIdx.y, bn = blockIdx.x;
  const int row = t >> 1, half = t & 1;
  const int lane = t & 63, wave = t >> 6;
  const int wm = wave >> 1, wn = wave & 1;
  const int quad = lane >> 4, l16 = lane & 15;

  f32x4 acc[4][4] = {};

  const float* xp = x + (size_t)(bm * 128 + row) * M_DIM + half * 16;
  const unsigned short* wh = Whi + (size_t)(bn * 128 + row) * M_DIM + half * 16;
  const unsigned short* wl = Wlo + (size_t)(bn * 128 + row) * M_DIM + half * 16;

  for (int k0 = 0; k0 < M_DIM; k0 += 32) {
    float4 v[4];
#pragma unroll
    for (int q = 0; q < 4; ++q) v[q] = *(const float4*)(xp + k0 + 4 * q);
    unsigned short hiv[16], lov[16];
#pragma unroll
    for (int q = 0; q < 4; ++q) {
      float fv[4] = {v[q].x, v[q].y, v[q].z, v[q].w};
#pragma unroll
      for (int e = 0; e < 4; ++e) {
        unsigned short h = f2bf(fv[e]);
        hiv[4 * q + e] = h;
        lov[4 * q + e] = f2bf(fv[e] - bf2f(h));
      }
    }
    *(uint4*)&Ah[row][half * 16]     = *(uint4*)&hiv[0];
    *(uint4*)&Ah[row][half * 16 + 8] = *(uint4*)&hiv[8];
    *(uint4*)&Al[row][half * 16]     = *(uint4*)&lov[0];
    *(uint4*)&Al[row][half * 16 + 8] = *(uint4*)&lov[8];
    *(uint4*)&Bh[row][half * 16]     = *(const uint4*)(wh + k0);
    *(uint4*)&Bh[row][half * 16 + 8] = *(const uint4*)(wh + k0 + 8);
    *(uint4*)&Bl[row][half * 16]     = *(const uint4*)(wl + k0);
    *(uint4*)&Bl[row][half * 16 + 8] = *(const uint4*)(wl + k0 + 8);
    __syncthreads();

    bf16x8 ah[4], al[4], bh[4], bl[4];
#pragma unroll
    for (int i = 0; i < 4; ++i) {
      ah[i] = *(const bf16x8*)&Ah[wm * 64 + i * 16 + l16][quad * 8];
      al[i] = *(const bf16x8*)&Al[wm * 64 + i * 16 + l16][quad * 8];
    }
#pragma unroll
    for (int j = 0; j < 4; ++j) {
      bh[j] = *(const bf16x8*)&Bh[wn * 64 + j * 16 + l16][quad * 8];
      bl[j] = *(const bf16x8*)&Bl[wn * 64 + j * 16 + l16][quad * 8];
    }
#pragma unroll
    for (int i = 0; i < 4; ++i)
#pragma unroll
      for (int j = 0; j < 4; ++j) {
        acc[i][j] = __builtin_amdgcn_mfma_f32_16x16x32_bf16(ah[i], bh[j], acc[i][j], 0, 0, 0);
        acc[i][j] = __builtin_amdgcn_mfma_f32_16x16x32_bf16(ah[i], bl[j], acc[i][j], 0, 0, 0);
        acc[i][j] = __builtin_amdgcn_mfma_f32_16x16x32_bf16(al[i], bh[j], acc[i][j], 0, 0, 0);
      }
    __syncthreads();
  }

#pragma unroll
  for (int i = 0; i < 4; ++i)
#pragma unroll
    for (int j = 0; j < 4; ++j) {
      int gcol = bn * 128 + wn * 64 + j * 16 + l16;
      float bv = bias[gcol];
#pragma unroll
      for (int r = 0; r < 4; ++r) {
        int grow = bm * 128 + wm * 64 + i * 16 + quad * 4 + r;
        drive[(size_t)grow * A_DIM + gcol] = acc[i][j][r] + bv;
      }
    }
}

// ---- fused settling loop: 9 recurrent steps, sigma LDS-resident ----
// Block: 64 rows, 512 threads (8 waves). Wave w owns output cols [w*64,w*64+64).
// sigma LDS layout: row r stride 512 bf16; granule (8 bf16 = 16B) g stored at
// slot g ^ (r&7)  -> conflict-free ds_read_b128 A-fragments.
// B-fragments (J hi/lo) are loaded per-lane directly from global (L2-hit):
// lane addr = row(l16-indexed)*512 + kb*64 + h*32 + quad*8; the two h-halves
// of each 128B line are issued back-to-back for full line consumption.
__global__ __launch_bounds__(512) void settle_kernel(
    const unsigned short* __restrict__ Jhi,
    const unsigned short* __restrict__ Jlo,
    const float* __restrict__ drive, float* __restrict__ outf) {
  __shared__ __align__(16) unsigned short smem[64 * 512];  // 64 KB

  const int t = threadIdx.x;
  const int lane = t & 63, w = t >> 6;
  const int quad = lane >> 4, l16 = lane & 15;
  const int r0 = blockIdx.x * 64;

  // drive -> registers in MFMA C/D layout (row = i*16+quad*4+rr, col = w*64+j*16+l16)
  float dreg[4][4][4];
#pragma unroll
  for (int i = 0; i < 4; ++i)
#pragma unroll
    for (int j = 0; j < 4; ++j) {
      const float* dp =
          drive + (size_t)(r0 + i * 16 + quad * 4) * A_DIM + w * 64 + j * 16 + l16;
#pragma unroll
      for (int rr = 0; rr < 4; ++rr) dreg[i][j][rr] = dp[(size_t)rr * A_DIM];
    }

  // sigma1 = tanh(drive) -> LDS (swizzled scalar b16 writes)
#pragma unroll
  for (int i = 0; i < 4; ++i)
#pragma unroll
    for (int rr = 0; rr < 4; ++rr) {
      const int r = i * 16 + quad * 4 + rr;
#pragma unroll
      for (int j = 0; j < 4; ++j) {
        const int c = w * 64 + j * 16 + l16;
        smem[r * 512 + (((c >> 3) ^ (r & 7)) << 3) + (c & 7)] =
            f2bf(fast_tanh(dreg[i][j][rr]));
      }
    }

  // per-lane J row pointers (4 col-fragments x hi/lo)
  const unsigned short* jph[4];
  const unsigned short* jpl[4];
#pragma unroll
  for (int j = 0; j < 4; ++j) {
    const size_t ro = (size_t)(w * 64 + j * 16 + l16) * A_DIM + quad * 8;
    jph[j] = Jhi + ro;
    jpl[j] = Jlo + ro;
  }
  // A-fragment LDS offsets (bf16 units), kb adds kb*64 (granule kb*8, XOR stays low-3)
  int abase[4][2];
#pragma unroll
  for (int i = 0; i < 4; ++i) {
    const int r = i * 16 + l16;
#pragma unroll
    for (int h = 0; h < 2; ++h)
      abase[i][h] = r * 512 + (((h * 4 + quad) ^ (r & 7)) << 3);
  }

  __syncthreads();

  for (int s = 0; s < 9; ++s) {
    f32x4 acc[4][4] = {};
    for (int kb = 0; kb < 8; ++kb) {
      const int k0 = kb * 64;
      bf16x8 a0[4], a1[4], bh0[4], bh1[4];
#pragma unroll
      for (int j = 0; j < 4; ++j) {           // hi: both 64B halves of each line
        bh0[j] = *(const bf16x8*)(jph[j] + k0);
        bh1[j] = *(const bf16x8*)(jph[j] + k0 + 32);
      }
#pragma unroll
      for (int i = 0; i < 4; ++i) {
        a0[i] = *(const bf16x8*)&smem[abase[i][0] + kb * 64];
        a1[i] = *(const bf16x8*)&smem[abase[i][1] + kb * 64];
      }
#pragma unroll
      for (int i = 0; i < 4; ++i)
#pragma unroll
        for (int j = 0; j < 4; ++j) {
          acc[i][j] = __builtin_amdgcn_mfma_f32_16x16x32_bf16(a0[i], bh0[j], acc[i][j], 0, 0, 0);
          acc[i][j] = __builtin_amdgcn_mfma_f32_16x16x32_bf16(a1[i], bh1[j], acc[i][j], 0, 0, 0);
        }
      bf16x8 bl0[4], bl1[4];
#pragma unroll
      for (int j = 0; j < 4; ++j) {           // lo: both 64B halves of each line
        bl0[j] = *(const bf16x8*)(jpl[j] + k0);
        bl1[j] = *(const bf16x8*)(jpl[j] + k0 + 32);
      }
#pragma unroll
      for (int i = 0; i < 4; ++i)
#pragma unroll
        for (int j = 0; j < 4; ++j) {
          acc[i][j] = __builtin_amdgcn_mfma_f32_16x16x32_bf16(a0[i], bl0[j], acc[i][j], 0, 0, 0);
          acc[i][j] = __builtin_amdgcn_mfma_f32_16x16x32_bf16(a1[i], bl1[j], acc[i][j], 0, 0, 0);
        }
    }

    if (s == 8) {  // final step: fp32 out, no sigma rewrite
#pragma unroll
      for (int i = 0; i < 4; ++i)
#pragma unroll
        for (int j = 0; j < 4; ++j) {
          float* op =
              outf + (size_t)(r0 + i * 16 + quad * 4) * A_DIM + w * 64 + j * 16 + l16;
#pragma unroll
          for (int rr = 0; rr < 4; ++rr)
            op[(size_t)rr * A_DIM] = fast_tanh(dreg[i][j][rr] + acc[i][j][rr]);
        }
    } else {
      __syncthreads();  // all waves done reading old sigma
#pragma unroll
      for (int i = 0; i < 4; ++i)
#pragma unroll
        for (int rr = 0; rr < 4; ++rr) {
          const int r = i * 16 + quad * 4 + rr;
#pragma unroll
          for (int j = 0; j < 4; ++j) {
            const int c = w * 64 + j * 16 + l16;
            smem[r * 512 + (((c >> 3) ^ (r & 7)) << 3) + (c & 7)] =
                f2bf(fast_tanh(dreg[i][j][rr] + acc[i][j][rr]));
          }
        }
      __syncthreads();  // new sigma visible to all waves
    }
  }
}

extern "C" void kernel_launch(void* const* d_in, const int* in_sizes, int n_in,
                              void* d_out, int out_size, void* d_ws, size_t ws_size,
                              hipStream_t stream) {
  const float* x = (const float*)d_in[0];
  const float* W = (const float*)d_in[1];
  const float* b = (const float*)d_in[2];
  const float* J = (const float*)d_in[3];
  float* out = (float*)d_out;

  char* ws = (char*)d_ws;
  float* drive        = (float*)(ws);                       // 33,554,432 B
  unsigned short* Whi = (unsigned short*)(ws + 33554432);   //  1,048,576 B
  unsigned short* Wlo = (unsigned short*)(ws + 34603008);   //  1,048,576 B
  unsigned short* Jhi = (unsigned short*)(ws + 35651584);   //    524,288 B
  unsigned short* Jlo = (unsigned short*)(ws + 36175872);   // end: 36,700,160

  const int nW = A_DIM * M_DIM;
  const int nJ = A_DIM * A_DIM;
  split_kernel<<<(nW + 255) / 256, 256, 0, stream>>>(W, Whi, Wlo, nW, 1.0f);
  split_kernel<<<(nJ + 255) / 256, 256, 0, stream>>>(J, Jhi, Jlo, nJ, 10.0f);

  dim3 dgrid(A_DIM / 128, B_DIM / 128);  // (4, 128)
  drive_kernel<<<dgrid, 256, 0, stream>>>(x, Whi, Wlo, b, drive);

  settle_kernel<<<B_DIM / 64, 512, 0, stream>>>(Jhi, Jlo, drive, out);
}